// Round 17
// baseline (63.450 us; speedup 1.0000x reference)
//
#include <hip/hip_runtime.h>
#include <math.h>

#define C_DIM 128
#define H_DIM 128
#define W_DIM 128
#define HW (H_DIM * W_DIM)
#define EPS_N 1e-12f
#define RST 4                  // rows per stripe
#define NSTR (H_DIM / RST)     // 32
#define SLC 16                 // channels per slice
#define NSL (C_DIM / SLC)      // 8
#define CPWV 4                 // channels per wave
#define NPL 11                 // 9 dots + fe2 + norm2
#define PS (NPL * W_DIM)       // 1408
#define LD2(p) (*(const float2*)(p))
#define LD4(p) (*(const float4*)(p))

// Register row-reuse: thread owns (col-pair x 4 rows) for its wave's 4 channels.
// Each fu row is loaded ONCE (float2 + one lft/rgt shuffle pair) and feeds the
// u/m/d taps of up to 3 output rows -> fu lane-traffic 1.5x (vs 3x in R8/R12),
// with NO LDS in the hot loop (R13's conflict/barrier regression avoided).
// All dk/w2 indexing is compile-time (unrolled j-loop) -> no scratch.

// ---------------- k2r: partial dots + fe2 + own-row fu-norm2 ----------------
__global__ __launch_bounds__(256) void k2r(const float* __restrict__ fe,
                                           const float* __restrict__ fu,
                                           float* __restrict__ pgA)
{
    __shared__ float red[4][NPL][W_DIM];   // 22.5 KB, row-multiplexed reduce

    const int tid = threadIdx.x;
    const int l   = tid & 63;
    const int wv  = tid >> 6;

    // XCD-chunked bijective swizzle (gridDim.x = 1024, % 8 == 0)
    const int bid = blockIdx.x;
    const int cpx = gridDim.x >> 3;
    const int wb  = (bid & 7) * cpx + (bid >> 3);
    const int sl  = wb & (NSL - 1);
    const int st  = (wb >> 3) & (NSTR - 1);
    const int bz  = wb >> 8;               // NSL*NSTR = 256

    const int r0   = st * RST;
    const int c0   = sl * SLC + wv * CPWV;
    const int col0 = 2 * l;
    const float2 z2 = make_float2(0.f, 0.f);

    float2 dk[RST][9];
    float2 fe2[RST], n2[RST];
#pragma unroll
    for (int t = 0; t < RST; ++t) {
        fe2[t] = z2; n2[t] = z2;
#pragma unroll
        for (int k = 0; k < 9; ++k) dk[t][k] = z2;
    }

    for (int ch = 0; ch < CPWV; ++ch) {
        const size_t cb = ((size_t)bz * C_DIM + c0 + ch) * HW;
        float2 fv[RST];
#pragma unroll
        for (int t = 0; t < RST; ++t) fv[t] = LD2(fe + cb + (r0 + t) * W_DIM + col0);
#pragma unroll
        for (int t = 0; t < RST; ++t) {
            fe2[t].x += fv[t].x * fv[t].x;
            fe2[t].y += fv[t].y * fv[t].y;
        }
#pragma unroll
        for (int j = 0; j < RST + 2; ++j) {
            const int gr = r0 - 1 + j;
            const float2 v = (gr >= 0 && gr < H_DIM) ? LD2(fu + cb + gr * W_DIM + col0) : z2;
            float lft = __shfl_up(v.y, 1);   if (l == 0)  lft = 0.f;
            float rgt = __shfl_down(v.x, 1); if (l == 63) rgt = 0.f;
            // u-tap (dr=0) for output row t = j (uses fu row t-1 = gr)
            if (j < RST) { const int t = j;
                dk[t][0].x += fv[t].x * lft; dk[t][1].x += fv[t].x * v.x; dk[t][2].x += fv[t].x * v.y;
                dk[t][0].y += fv[t].y * v.x; dk[t][1].y += fv[t].y * v.y; dk[t][2].y += fv[t].y * rgt; }
            // m-tap (dr=1) for t = j-1 (own row); also own-row norm2
            if (j >= 1 && j <= RST) { const int t = j - 1;
                n2[t].x += v.x * v.x; n2[t].y += v.y * v.y;
                dk[t][3].x += fv[t].x * lft; dk[t][4].x += fv[t].x * v.x; dk[t][5].x += fv[t].x * v.y;
                dk[t][3].y += fv[t].y * v.x; dk[t][4].y += fv[t].y * v.y; dk[t][5].y += fv[t].y * rgt; }
            // d-tap (dr=2) for t = j-2 (uses fu row t+1 = gr)
            if (j >= 2) { const int t = j - 2;
                dk[t][6].x += fv[t].x * lft; dk[t][7].x += fv[t].x * v.x; dk[t][8].x += fv[t].x * v.y;
                dk[t][6].y += fv[t].y * v.x; dk[t][7].y += fv[t].y * v.y; dk[t][8].y += fv[t].y * rgt; }
        }
    }

    // row-multiplexed 4-slot reduce -> pgA[RG][slice][plane][col]
    const int RGb = bz * H_DIM + r0;
#pragma unroll
    for (int t = 0; t < RST; ++t) {
#pragma unroll
        for (int k = 0; k < 9; ++k) *(float2*)&red[wv][k][col0] = dk[t][k];
        *(float2*)&red[wv][9][col0]  = fe2[t];
        *(float2*)&red[wv][10][col0] = n2[t];
        __syncthreads();
        float* dst = pgA + ((size_t)(RGb + t) * NSL + sl) * PS;
        const float* r0p = &red[0][0][0];
        const float* r1p = &red[1][0][0];
        const float* r2p = &red[2][0][0];
        const float* r3p = &red[3][0][0];
        for (int q = tid; q < PS; q += 256)
            dst[q] = r0p[q] + r1p[q] + r2p[q] + r3p[q];
        __syncthreads();
    }
}

// ---------------- k25: reduce partials across the 8 slices (R13-measured) ----------------
__global__ __launch_bounds__(256) void k25(const float* __restrict__ pgA,
                                           float* __restrict__ pgB,
                                           float* __restrict__ pgN)
{
    const int tid = threadIdx.x;
    const int RG0 = blockIdx.x * 2;
    for (int t = tid; t < 2 * NPL * 32; t += 256) {
        const int r = t / (NPL * 32);
        const int rem = t - r * (NPL * 32);
        const int pl = rem >> 5, c4 = (rem & 31) * 4;
        const int RG = RG0 + r;
        const float* src = pgA + (size_t)RG * NSL * PS + pl * W_DIM + c4;
        float4 s = make_float4(0.f, 0.f, 0.f, 0.f);
#pragma unroll
        for (int s8 = 0; s8 < NSL; ++s8) {
            const float4 v = LD4(src + (size_t)s8 * PS);
            s.x += v.x; s.y += v.y; s.z += v.z; s.w += v.w;
        }
        if (pl < 10) {
            *(float4*)&pgB[((size_t)RG * 10 + pl) * W_DIM + c4] = s;
        } else {
            float4 rr;
            rr.x = 1.f / fmaxf(sqrtf(s.x), EPS_N);
            rr.y = 1.f / fmaxf(sqrtf(s.y), EPS_N);
            rr.z = 1.f / fmaxf(sqrtf(s.z), EPS_N);
            rr.w = 1.f / fmaxf(sqrtf(s.w), EPS_N);
            *(float4*)&pgN[(size_t)RG * W_DIM + c4] = rr;
        }
    }
}

// ---------------- k3r: per-thread softmax + row-reuse aggregation (no LDS) ----------------
__global__ __launch_bounds__(256) void k3r(const float* __restrict__ fe,
                                           const float* __restrict__ fu,
                                           const float* __restrict__ pgB,
                                           const float* __restrict__ pgN,
                                           float* __restrict__ out)
{
    const int tid = threadIdx.x;
    const int l   = tid & 63;
    const int wv  = tid >> 6;

    const int bid = blockIdx.x;
    const int cpx = gridDim.x >> 3;
    const int wb  = (bid & 7) * cpx + (bid >> 3);
    const int sl  = wb & (NSL - 1);
    const int st  = (wb >> 3) & (NSTR - 1);
    const int bz  = wb >> 8;

    const int r0   = st * RST;
    const int c0   = sl * SLC + wv * CPWV;
    const int col0 = 2 * l;
    const float2 z2 = make_float2(0.f, 0.f);

    // per-thread softmax weights for 2 px x RST rows (R13-measured k3s formula)
    float2 w2[RST][9];
#pragma unroll
    for (int t = 0; t < RST; ++t) {
        const int row = r0 + t;
        const int RG  = bz * H_DIM + row;
        const float* db = pgB + (size_t)RG * 10 * W_DIM;
        const float2 f2 = LD2(&db[9 * W_DIM + col0]);
        const float rfx = 1.f / fmaxf(sqrtf(f2.x), EPS_N);
        const float rfy = 1.f / fmaxf(sqrtf(f2.y), EPS_N);
        float csx[9], csy[9];
        float mxx = -1e30f, mxy = -1e30f;
#pragma unroll
        for (int k = 0; k < 9; ++k) {
            const int di = k / 3, dj = k % 3;
            const int nr = row + di - 1;
            const int nrc = min(max(nr, 0), H_DIM - 1);
            const float2 dv = LD2(&db[k * W_DIM + col0]);
            const float* np = pgN + (size_t)(bz * H_DIM + nrc) * W_DIM;
            { const int nc = col0 + dj - 1;
              const bool ok = (nr >= 0 && nr < H_DIM && nc >= 0 && nc < W_DIM);
              const int ncc = min(max(nc, 0), W_DIM - 1);
              const float cv = ok ? dv.x * rfx * np[ncc] : 0.f;
              csx[k] = cv; mxx = fmaxf(mxx, cv); }
            { const int nc = col0 + dj;
              const bool ok = (nr >= 0 && nr < H_DIM && nc >= 0 && nc < W_DIM);
              const int ncc = min(max(nc, 0), W_DIM - 1);
              const float cv = ok ? dv.y * rfy * np[ncc] : 0.f;
              csy[k] = cv; mxy = fmaxf(mxy, cv); }
        }
        float sx = 0.f, sy = 0.f;
#pragma unroll
        for (int k = 0; k < 9; ++k) {
            csx[k] = __expf(csx[k] - mxx); sx += csx[k];
            csy[k] = __expf(csy[k] - mxy); sy += csy[k];
        }
        const float isx = 1.f / sx, isy = 1.f / sy;
#pragma unroll
        for (int k = 0; k < 9; ++k) {
            w2[t][k].x = csx[k] * isx;
            w2[t][k].y = csy[k] * isy;
        }
    }

    // row-reuse aggregation + residual (fu rows loaded once; no LDS, no barriers)
    for (int ch = 0; ch < CPWV; ++ch) {
        const size_t cb = ((size_t)bz * C_DIM + c0 + ch) * HW;
        float2 acc[RST];
#pragma unroll
        for (int t = 0; t < RST; ++t) acc[t] = LD2(fe + cb + (r0 + t) * W_DIM + col0);
#pragma unroll
        for (int j = 0; j < RST + 2; ++j) {
            const int gr = r0 - 1 + j;
            const float2 v = (gr >= 0 && gr < H_DIM) ? LD2(fu + cb + gr * W_DIM + col0) : z2;
            float lft = __shfl_up(v.y, 1);   if (l == 0)  lft = 0.f;
            float rgt = __shfl_down(v.x, 1); if (l == 63) rgt = 0.f;
            if (j < RST) { const int t = j;          // u-tap
                acc[t].x += w2[t][0].x * lft + w2[t][1].x * v.x + w2[t][2].x * v.y;
                acc[t].y += w2[t][0].y * v.x + w2[t][1].y * v.y + w2[t][2].y * rgt; }
            if (j >= 1 && j <= RST) { const int t = j - 1;   // m-tap
                acc[t].x += w2[t][3].x * lft + w2[t][4].x * v.x + w2[t][5].x * v.y;
                acc[t].y += w2[t][3].y * v.x + w2[t][4].y * v.y + w2[t][5].y * rgt; }
            if (j >= 2) { const int t = j - 2;       // d-tap
                acc[t].x += w2[t][6].x * lft + w2[t][7].x * v.x + w2[t][8].x * v.y;
                acc[t].y += w2[t][6].y * v.x + w2[t][7].y * v.y + w2[t][8].y * rgt; }
        }
#pragma unroll
        for (int t = 0; t < RST; ++t)
            *(float2*)(out + cb + (r0 + t) * W_DIM + col0) = acc[t];
    }
}

extern "C" void kernel_launch(void* const* d_in, const int* in_sizes, int n_in,
                              void* d_out, int out_size, void* d_ws, size_t ws_size,
                              hipStream_t stream) {
    const float* fe = (const float*)d_in[0];   // fe_lv
    const float* fu = (const float*)d_in[1];   // fused_features
    float* out = (float*)d_out;
    const int B = in_sizes[0] / (C_DIM * HW);
    const int RGtot = B * H_DIM;

    float* pgA = (float*)d_ws;                       // RGtot*8*1408 (23 MB @ B=4)
    float* pgB = pgA + (size_t)RGtot * NSL * PS;     // RGtot*10*128 (2.6 MB)
    float* pgN = pgB + (size_t)RGtot * 10 * W_DIM;   // RGtot*128    (0.26 MB)

    dim3 g(B * NSTR * NSL);                   // 1024 blocks @ B=4 (%8==0)
    k2r<<<g, 256, 0, stream>>>(fe, fu, pgA);

    dim3 g25(RGtot / 2);                      // 256 blocks
    k25<<<g25, 256, 0, stream>>>(pgA, pgB, pgN);

    k3r<<<g, 256, 0, stream>>>(fe, fu, pgB, pgN, out);
}

// Round 18
// 58.286 us; speedup vs baseline: 1.0886x; 1.0886x over previous
//
#include <hip/hip_runtime.h>
#include <math.h>

#define C_DIM 128
#define H_DIM 128
#define W_DIM 128
#define HW (H_DIM * W_DIM)
#define EPS_N 1e-12f
#define NT 512
#define NW 8        // waves per block
#define CPW 16      // channels per wave
#define LD4(p) (*(const float4*)(p))

// ---------------- kernel 1: reciprocal clamped L2 norm of fused over C ----------------
// R9-measured-passing, verbatim.
__global__ __launch_bounds__(256) void norms_fu4(const float* __restrict__ fu,
                                                 float* __restrict__ rn)
{
    __shared__ float4 part[32][9];
    const int tid = threadIdx.x;
    const int li = tid & 31;
    const int g = tid >> 5;
    const float* p = fu + (size_t)blockIdx.y * C_DIM * HW + (size_t)g * 16 * HW
                     + blockIdx.x * 128 + 4 * li;
    float4 s = make_float4(0.f, 0.f, 0.f, 0.f);
#pragma unroll
    for (int j = 0; j < 16; ++j) {
        const float4 v = LD4(p + (size_t)j * HW);
        s.x += v.x * v.x; s.y += v.y * v.y;
        s.z += v.z * v.z; s.w += v.w * v.w;
    }
    part[li][g] = s;
    __syncthreads();
    if (tid < 32) {
        float4 t = make_float4(0.f, 0.f, 0.f, 0.f);
#pragma unroll
        for (int gg = 0; gg < 8; ++gg) {
            const float4 q = part[tid][gg];
            t.x += q.x; t.y += q.y; t.z += q.z; t.w += q.w;
        }
        float4 r;
        r.x = 1.f / fmaxf(sqrtf(t.x), EPS_N);
        r.y = 1.f / fmaxf(sqrtf(t.y), EPS_N);
        r.z = 1.f / fmaxf(sqrtf(t.z), EPS_N);
        r.w = 1.f / fmaxf(sqrtf(t.w), EPS_N);
        *(float4*)(rn + (size_t)blockIdx.y * HW + blockIdx.x * 128 + 4 * tid) = r;
    }
}

// ---------------- kernel 2: dots + softmax + aggregation (SHUFFLE-FREE hot loops) ----------------
// R8 structure (best measured: 38.3us) with the column-neighbor taps sourced from
// overlapping global loads (1 aligned float4 + 2 clamped scalars per row-tap)
// instead of DS shuffles. Removes all lgkmcnt interleave from the inner loops ->
// VMEM queue can batch deeply (theory: the 3-way 38us plateau is DS-wait-bound).
// Lane map (R12-measured): li = l&31 owns px 4li..4li+3; sub = l>>5 channel parity;
// one shfl_xor(32) combine per pass (outside hot loop).
__global__ __launch_bounds__(NT) void asfr_main5(const float* __restrict__ fe,
                                                 const float* __restrict__ fu,
                                                 const float* __restrict__ rn,
                                                 float* __restrict__ out)
{
    __shared__ float part[NW][10][W_DIM];  // 40 KB: [wave][9 dots + fe2][px]
    __shared__ float wl[9][W_DIM];         // 4.5 KB softmax weights
    __shared__ float n2r[3][W_DIM];        // 1.5 KB staged reciprocal fu norms

    const int tid = threadIdx.x;
    const int l   = tid & 63;
    const int wv  = tid >> 6;
    const int li  = l & 31;
    const int sub = l >> 5;

    // XCD-chunked bijective swizzle (gridDim.x % 8 == 0)
    const int bid = blockIdx.x;
    const int cpx = gridDim.x >> 3;
    const int wb  = (bid & 7) * cpx + (bid >> 3);
    const int bz  = wb >> 7;
    const int row = wb & 127;

    const size_t imgbase = (size_t)bz * C_DIM * HW;
    const int c0  = wv * CPW;
    const int px0 = 4 * li;

    // stage n2r for rows row-1,row,row+1 (R8-measured; 384 < NT)
    if (tid < 3 * W_DIM) {
        const int r = tid >> 7, c = tid & 127;
        const int nr = row + r - 1;
        float v = 1.f;
        if (nr >= 0 && nr < H_DIM) v = rn[(size_t)bz * HW + nr * W_DIM + c];
        n2r[r][c] = v;
    }

    const bool has_u = (row > 0), has_d = (row < H_DIM - 1);
    const int rup = has_u ? row - 1 : row;   // clamped; values masked below
    const int rdn = has_d ? row + 1 : row;
    const float4 z4 = make_float4(0.f, 0.f, 0.f, 0.f);

    // in-bounds offsets for the neighbor scalars (values masked at edges)
    const int offL = (li == 0) ? 0 : -1;
    const int offR = (li == 31) ? 3 : 4;

    float4 dk[9];
#pragma unroll
    for (int k = 0; k < 9; ++k) dk[k] = z4;
    float4 fe24 = z4;

// one row-tap: aligned float4 + 2 overlapping scalars; no cross-lane ops
#define TAP(P, ZR, F, R3) {                                                   \
    float4 m_ = LD4(P);                                                       \
    float lf_ = (P)[offL];                                                    \
    float rf_ = (P)[offR];                                                    \
    if (ZR) m_ = z4;                                                          \
    if ((li == 0) || (ZR)) lf_ = 0.f;                                         \
    if ((li == 31) || (ZR)) rf_ = 0.f;                                        \
    dk[R3+0].x += F.x*lf_;  dk[R3+0].y += F.y*m_.x;                           \
    dk[R3+0].z += F.z*m_.y; dk[R3+0].w += F.w*m_.z;                           \
    dk[R3+1].x += F.x*m_.x; dk[R3+1].y += F.y*m_.y;                           \
    dk[R3+1].z += F.z*m_.z; dk[R3+1].w += F.w*m_.w;                           \
    dk[R3+2].x += F.x*m_.y; dk[R3+2].y += F.y*m_.z;                           \
    dk[R3+2].z += F.z*m_.w; dk[R3+2].w += F.w*rf_; }

    // ---------------- pass 1: dots + ||fe||^2 ----------------
#pragma unroll
    for (int j = 0; j < 8; ++j) {
        const size_t cb = imgbase + (size_t)(c0 + 2 * j + sub) * HW;
        const float4 f = LD4(fe + cb + row * W_DIM + px0);
        fe24.x += f.x * f.x; fe24.y += f.y * f.y;
        fe24.z += f.z * f.z; fe24.w += f.w * f.w;
        const float* pu = fu + cb + rup * W_DIM + px0;
        const float* pm = fu + cb + row * W_DIM + px0;
        const float* pd = fu + cb + rdn * W_DIM + px0;
        TAP(pu, !has_u, f, 0)
        TAP(pm, false,  f, 3)
        TAP(pd, !has_d, f, 6)
    }
#undef TAP

    // combine channel-parity halves (R12-measured; once per pass, outside hot loop)
#pragma unroll
    for (int k = 0; k < 9; ++k) {
        dk[k].x += __shfl_xor(dk[k].x, 32);
        dk[k].y += __shfl_xor(dk[k].y, 32);
        dk[k].z += __shfl_xor(dk[k].z, 32);
        dk[k].w += __shfl_xor(dk[k].w, 32);
    }
    fe24.x += __shfl_xor(fe24.x, 32); fe24.y += __shfl_xor(fe24.y, 32);
    fe24.z += __shfl_xor(fe24.z, 32); fe24.w += __shfl_xor(fe24.w, 32);

    if (sub == 0) {
#pragma unroll
        for (int k = 0; k < 9; ++k) *(float4*)&part[wv][k][px0] = dk[k];
        *(float4*)&part[wv][9][px0] = fe24;
    }
    __syncthreads();

    // ---------------- softmax (threads 0..127, one per pixel; R8-measured) ----------------
    if (tid < W_DIM) {
        const int px = tid;
        float dv[10];
#pragma unroll
        for (int k = 0; k < 10; ++k) {
            float s = 0.f;
#pragma unroll
            for (int w = 0; w < NW; ++w) s += part[w][k][px];
            dv[k] = s;
        }
        const float rfe = 1.f / fmaxf(sqrtf(dv[9]), EPS_N);
        float cs[9];
        float mx = -1e30f;
#pragma unroll
        for (int k = 0; k < 9; ++k) {
            const int di = k / 3, dj = k % 3;
            const int nr = row + di - 1;
            const int nc = px + dj - 1;
            const bool ok = (nr >= 0 && nr < H_DIM && nc >= 0 && nc < W_DIM);
            const int ncc = min(max(nc, 0), W_DIM - 1);
            const float cv = ok ? dv[k] * rfe * n2r[di][ncc] : 0.f;
            cs[k] = cv;
            mx = fmaxf(mx, cv);
        }
        float sum = 0.f;
#pragma unroll
        for (int k = 0; k < 9; ++k) { cs[k] = __expf(cs[k] - mx); sum += cs[k]; }
        const float is = 1.f / sum;
#pragma unroll
        for (int k = 0; k < 9; ++k) wl[k][px] = cs[k] * is;
    }
    __syncthreads();

    // ---------------- pass 2: aggregation + residual (shuffle-free) ----------------
    float4 w4[9];
#pragma unroll
    for (int k = 0; k < 9; ++k) w4[k] = *(const float4*)&wl[k][px0];

#define AGTAP(P, ZR, ACC, R3) {                                               \
    float4 m_ = LD4(P);                                                       \
    float lf_ = (P)[offL];                                                    \
    float rf_ = (P)[offR];                                                    \
    if (ZR) m_ = z4;                                                          \
    if ((li == 0) || (ZR)) lf_ = 0.f;                                         \
    if ((li == 31) || (ZR)) rf_ = 0.f;                                        \
    ACC.x += w4[R3+0].x*lf_  + w4[R3+1].x*m_.x + w4[R3+2].x*m_.y;             \
    ACC.y += w4[R3+0].y*m_.x + w4[R3+1].y*m_.y + w4[R3+2].y*m_.z;             \
    ACC.z += w4[R3+0].z*m_.y + w4[R3+1].z*m_.z + w4[R3+2].z*m_.w;             \
    ACC.w += w4[R3+0].w*m_.z + w4[R3+1].w*m_.w + w4[R3+2].w*rf_; }

#pragma unroll
    for (int j = 0; j < 8; ++j) {
        const size_t cb = imgbase + (size_t)(c0 + 2 * j + sub) * HW;
        const float4 f = LD4(fe + cb + row * W_DIM + px0);
        const float* pu = fu + cb + rup * W_DIM + px0;
        const float* pm = fu + cb + row * W_DIM + px0;
        const float* pd = fu + cb + rdn * W_DIM + px0;
        float4 acc = f;   // residual
        AGTAP(pu, !has_u, acc, 0)
        AGTAP(pm, false,  acc, 3)
        AGTAP(pd, !has_d, acc, 6)
        *(float4*)(out + cb + row * W_DIM + px0) = acc;
    }
#undef AGTAP
}

extern "C" void kernel_launch(void* const* d_in, const int* in_sizes, int n_in,
                              void* d_out, int out_size, void* d_ws, size_t ws_size,
                              hipStream_t stream) {
    const float* fe = (const float*)d_in[0];   // fe_lv
    const float* fu = (const float*)d_in[1];   // fused_features
    float* out = (float*)d_out;
    float* rn = (float*)d_ws;                  // B*HW floats
    const int B = in_sizes[0] / (C_DIM * HW);

    dim3 g1(HW / 128, B);
    norms_fu4<<<g1, 256, 0, stream>>>(fu, rn);

    dim3 g2(B * H_DIM);
    asfr_main5<<<g2, NT, 0, stream>>>(fe, fu, rn, out);
}

// Round 20
// 38.857 us; speedup vs baseline: 1.6329x; 1.5000x over previous
//
#include <hip/hip_runtime.h>
#include <math.h>

#define C_DIM 128
#define H_DIM 128
#define W_DIM 128
#define HW (H_DIM * W_DIM)
#define EPS_N 1e-12f
#define NT 512
#define NW 8        // waves per block
#define CPW 16      // channels per wave
#define LD2(p) (*(const float2*)(p))
#define LD4(p) (*(const float4*)(p))

// ---------------- kernel 1: reciprocal clamped L2 norm of fused over C ----------------
// R9-measured-passing float4 version (G13: vectorized loads for memory-bound reduce).
__global__ __launch_bounds__(256) void norms_fu4(const float* __restrict__ fu,
                                                 float* __restrict__ rn)
{
    __shared__ float4 part[32][9];   // [lane][group], pad 9
    const int tid = threadIdx.x;
    const int li = tid & 31;
    const int g = tid >> 5;
    const float* p = fu + (size_t)blockIdx.y * C_DIM * HW + (size_t)g * 16 * HW
                     + blockIdx.x * 128 + 4 * li;
    float4 s = make_float4(0.f, 0.f, 0.f, 0.f);
#pragma unroll
    for (int j = 0; j < 16; ++j) {
        const float4 v = LD4(p + (size_t)j * HW);
        s.x += v.x * v.x; s.y += v.y * v.y;
        s.z += v.z * v.z; s.w += v.w * v.w;
    }
    part[li][g] = s;
    __syncthreads();
    if (tid < 32) {
        float4 t = make_float4(0.f, 0.f, 0.f, 0.f);
#pragma unroll
        for (int gg = 0; gg < 8; ++gg) {
            const float4 q = part[tid][gg];
            t.x += q.x; t.y += q.y; t.z += q.z; t.w += q.w;
        }
        float4 r;
        r.x = 1.f / fmaxf(sqrtf(t.x), EPS_N);
        r.y = 1.f / fmaxf(sqrtf(t.y), EPS_N);
        r.z = 1.f / fmaxf(sqrtf(t.z), EPS_N);
        r.w = 1.f / fmaxf(sqrtf(t.w), EPS_N);
        *(float4*)(rn + (size_t)blockIdx.y * HW + blockIdx.x * 128 + 4 * tid) = r;
    }
}

// ---------------- kernel 2: dots + softmax + aggregation ----------------
// R8-measured-passing (38.26 us total), verbatim. Block = one image row, 8 waves;
// wave wv owns channels [16wv,16wv+16); lane l owns pixels 2l,2l+1; column
// neighbors via masked shuffles; channels batched 2 at a time (8 loads in flight).
__global__ __launch_bounds__(NT) void asfr_main2(const float* __restrict__ fe,
                                                 const float* __restrict__ fu,
                                                 const float* __restrict__ rn,
                                                 float* __restrict__ out)
{
    __shared__ float part[NW][10][W_DIM];  // 40 KB: [wave][9 dots + fe2][px]
    __shared__ float wl[9][W_DIM];         // 4.5 KB softmax weights
    __shared__ float n2r[3][W_DIM];        // 1.5 KB staged reciprocal fu norms

    const int tid = threadIdx.x;
    const int l   = tid & 63;
    const int wv  = tid >> 6;

    // XCD-chunked bijective swizzle (gridDim.x % 8 == 0)
    const int bid = blockIdx.x;
    const int cpx = gridDim.x >> 3;
    const int wb  = (bid & 7) * cpx + (bid >> 3);
    const int bz  = wb >> 7;
    const int row = wb & 127;

    const size_t imgbase = (size_t)bz * C_DIM * HW;
    const int c0   = wv * CPW;
    const int col0 = 2 * l;

    // stage n2r for rows row-1,row,row+1 (384 < NT=512)
    if (tid < 3 * W_DIM) {
        const int r = tid >> 7, c = tid & 127;
        const int nr = row + r - 1;
        float v = 1.f;
        if (nr >= 0 && nr < H_DIM) v = rn[(size_t)bz * HW + nr * W_DIM + c];
        n2r[r][c] = v;
    }

    const bool has_u = (row > 0), has_d = (row < H_DIM - 1);
    const int rup = has_u ? row - 1 : row;   // clamped; loads zeroed below
    const int rdn = has_d ? row + 1 : row;

    const float* pfe = fe + imgbase + (size_t)c0 * HW + row * W_DIM + col0;
    const float* pfm = fu + imgbase + (size_t)c0 * HW + row * W_DIM + col0;
    const float* pfu = fu + imgbase + (size_t)c0 * HW + rup * W_DIM + col0;
    const float* pfd = fu + imgbase + (size_t)c0 * HW + rdn * W_DIM + col0;
    const float2 z2 = make_float2(0.f, 0.f);

    float2 dk[9];
#pragma unroll
    for (int k = 0; k < 9; ++k) dk[k] = z2;
    float2 fe2 = z2;

    auto acc3 = [&](const float2 f, const float2 v, const int r3) {
        float lft = __shfl_up(v.y, 1);   lft = (l == 0)  ? 0.f : lft;   // col 2l-1
        float rgt = __shfl_down(v.x, 1); rgt = (l == 63) ? 0.f : rgt;   // col 2l+2
        dk[r3+0].x += f.x * lft;  dk[r3+1].x += f.x * v.x;  dk[r3+2].x += f.x * v.y;
        dk[r3+0].y += f.y * v.x;  dk[r3+1].y += f.y * v.y;  dk[r3+2].y += f.y * rgt;
    };

    // ---------------- pass 1: dots + ||fe||^2 (2 channels per batch) ----------------
#pragma unroll
    for (int jb = 0; jb < CPW / 2; ++jb) {
        const size_t offA = (size_t)(2 * jb) * HW;
        const size_t offB = offA + HW;
        float2 fA = LD2(pfe + offA); float2 uA = LD2(pfu + offA);
        float2 mA = LD2(pfm + offA); float2 dA = LD2(pfd + offA);
        float2 fB = LD2(pfe + offB); float2 uB = LD2(pfu + offB);
        float2 mB = LD2(pfm + offB); float2 dB = LD2(pfd + offB);
        if (!has_u) { uA = z2; uB = z2; }
        if (!has_d) { dA = z2; dB = z2; }
        fe2.x += fA.x * fA.x + fB.x * fB.x;
        fe2.y += fA.y * fA.y + fB.y * fB.y;
        acc3(fA, uA, 0); acc3(fA, mA, 3); acc3(fA, dA, 6);
        acc3(fB, uB, 0); acc3(fB, mB, 3); acc3(fB, dB, 6);
    }

    // per-wave partials (direct 8-slot layout)
#pragma unroll
    for (int k = 0; k < 9; ++k) *(float2*)&part[wv][k][col0] = dk[k];
    *(float2*)&part[wv][9][col0] = fe2;
    __syncthreads();

    // ---------------- softmax (threads 0..127, one per pixel) ----------------
    if (tid < W_DIM) {
        const int px = tid;
        float dv[10];
#pragma unroll
        for (int k = 0; k < 10; ++k) {
            float s = 0.f;
#pragma unroll
            for (int w = 0; w < NW; ++w) s += part[w][k][px];
            dv[k] = s;
        }
        const float rfe = 1.f / fmaxf(sqrtf(dv[9]), EPS_N);
        float cs[9];
        float mx = -1e30f;
#pragma unroll
        for (int k = 0; k < 9; ++k) {
            const int di = k / 3, dj = k % 3;
            const int nr = row + di - 1;
            const int nc = px + dj - 1;
            const bool ok = (nr >= 0 && nr < H_DIM && nc >= 0 && nc < W_DIM);
            const int ncc = min(max(nc, 0), W_DIM - 1);
            const float cv = ok ? dv[k] * rfe * n2r[di][ncc] : 0.f;
            cs[k] = cv;
            mx = fmaxf(mx, cv);
        }
        float sum = 0.f;
#pragma unroll
        for (int k = 0; k < 9; ++k) { cs[k] = __expf(cs[k] - mx); sum += cs[k]; }
        const float is = 1.f / sum;
#pragma unroll
        for (int k = 0; k < 9; ++k) wl[k][px] = cs[k] * is;
    }
    __syncthreads();

    // ---------------- pass 2: weighted aggregation + residual ----------------
    float2 w2[9];
#pragma unroll
    for (int k = 0; k < 9; ++k) w2[k] = *(const float2*)&wl[k][col0];

    auto agg3 = [&](float2& acc, const float2 v, const int r3) {
        float lft = __shfl_up(v.y, 1);   lft = (l == 0)  ? 0.f : lft;
        float rgt = __shfl_down(v.x, 1); rgt = (l == 63) ? 0.f : rgt;
        acc.x += w2[r3+0].x * lft  + w2[r3+1].x * v.x + w2[r3+2].x * v.y;
        acc.y += w2[r3+0].y * v.x  + w2[r3+1].y * v.y + w2[r3+2].y * rgt;
    };

    float* pout = out + imgbase + (size_t)c0 * HW + row * W_DIM + col0;
#pragma unroll
    for (int jb = 0; jb < CPW / 2; ++jb) {
        const size_t offA = (size_t)(2 * jb) * HW;
        const size_t offB = offA + HW;
        float2 fA = LD2(pfe + offA); float2 uA = LD2(pfu + offA);
        float2 mA = LD2(pfm + offA); float2 dA = LD2(pfd + offA);
        float2 fB = LD2(pfe + offB); float2 uB = LD2(pfu + offB);
        float2 mB = LD2(pfm + offB); float2 dB = LD2(pfd + offB);
        if (!has_u) { uA = z2; uB = z2; }
        if (!has_d) { dA = z2; dB = z2; }
        float2 accA = fA;   // residual
        float2 accB = fB;
        agg3(accA, uA, 0); agg3(accA, mA, 3); agg3(accA, dA, 6);
        agg3(accB, uB, 0); agg3(accB, mB, 3); agg3(accB, dB, 6);
        *(float2*)(pout + offA) = accA;
        *(float2*)(pout + offB) = accB;
    }
}

extern "C" void kernel_launch(void* const* d_in, const int* in_sizes, int n_in,
                              void* d_out, int out_size, void* d_ws, size_t ws_size,
                              hipStream_t stream) {
    const float* fe = (const float*)d_in[0];   // fe_lv
    const float* fu = (const float*)d_in[1];   // fused_features
    float* out = (float*)d_out;
    float* rn = (float*)d_ws;                  // B*HW floats
    const int B = in_sizes[0] / (C_DIM * HW);

    dim3 g1(HW / 128, B);
    norms_fu4<<<g1, 256, 0, stream>>>(fu, rn);

    dim3 g2(B * H_DIM);
    asfr_main2<<<g2, NT, 0, stream>>>(fe, fu, rn, out);
}